// Round 6
// baseline (153.380 us; speedup 1.0000x reference)
//
#include <hip/hip_runtime.h>

#define THR_F     0.2f
#define TANH_THR  0.19737532f   // tanh(0.2), fp32-rounded

// ---------------------------------------------------------------------------
// helpers
// ---------------------------------------------------------------------------
__device__ __forceinline__ float fast_tanh(float x) {
    x = fminf(10.f, fmaxf(-10.f, x));
    float e = __expf(2.f * x);
    return (e - 1.f) * __builtin_amdgcn_rcpf(e + 1.f);
}

// monotone float <-> uint key for atomicMax on floats (all our values > -2)
__device__ __forceinline__ unsigned fkey(float f) {
    unsigned u = __float_as_uint(f);
    return (u & 0x80000000u) ? ~u : (u | 0x80000000u);
}
__device__ __forceinline__ float fdecode(unsigned u) {
    return __uint_as_float((u & 0x80000000u) ? (u & 0x7FFFFFFFu) : ~u);
}

// ---------------------------------------------------------------------------
// Kernel 0: prep. Grid = 610 blocks x 64 threads.
//  blocks 0..383   : (b,n) -> base[b*24+n] = dot(nullary[b],K[n,0:128])
//                    + THR - ssq[n]*tanh(THR)
//  blocks 384..479 : pack Wb[k][48] (binary weight cols 384:512|512:640) and
//                    WuT[48][128] (unary cols 128:256|256:384, n-major)
//  blocks 480..609 : zero max0[128] + slots1[8192]
// and_kernel layout: (3,8,640), ac = a*8+c rows of 640:
//   cols 0:128 null | 128:256 u(o0) | 256:384 u(o1) | 384:512 b(o0,j01) | 512:640 b(o1,j10)
// ---------------------------------------------------------------------------
__global__ __launch_bounds__(64) void prep_kernel(
    const float* __restrict__ nullary,   // [16][128]
    const float* __restrict__ andk,      // [24][640]
    float* __restrict__ Wb,              // [128][48]
    float* __restrict__ WuT,             // [48][128]
    float* __restrict__ base,            // [16][24]
    unsigned* __restrict__ zzero)        // max0[128] ++ slots1[8192]
{
    const int bid = blockIdx.x;
    const int t   = threadIdx.x;
    if (bid < 384) {
        const int b = bid / 24, n = bid % 24;
        const float* w  = andk + n * 640;
        const float* nu = nullary + b * 128;
        float s = 0.f;
        #pragma unroll
        for (int i = 0; i < 10; ++i) { float v = w[t + i * 64]; s = fmaf(v, v, s); }
        float d = fmaf(nu[t], w[t], 0.f);
        d = fmaf(nu[t + 64], w[t + 64], d);
        #pragma unroll
        for (int m = 32; m; m >>= 1) {
            s += __shfl_xor(s, m, 64);
            d += __shfl_xor(d, m, 64);
        }
        if (t == 0) base[bid] = d + THR_F - s * TANH_THR;
    } else if (bid < 480) {
        const int i = (bid - 384) * 64 + t;   // 0..6143
        // Wb[k][48]: k = i/48, n = i%48
        {
            const int k = i / 48, n = i % 48;
            const int ac  = (n < 24) ? n : n - 24;
            const int col = (n < 24) ? 384 : 512;
            Wb[i] = andk[ac * 640 + col + k];
        }
        // WuT[n][128]: n = i/128, k = i%128
        {
            const int n = i / 128, k = i % 128;
            const int ac  = (n < 24) ? n : n - 24;
            const int col = (n < 24) ? 128 : 256;
            WuT[i] = andk[ac * 640 + col + k];
        }
    } else {
        const int idx = (bid - 480) * 64 + t;
        if (idx < 8320) zzero[idx] = 0u;
    }
}

// ---------------------------------------------------------------------------
// Kernel 1: FUSED projection + tanh + reductions + OR stage.
// Objects tiled into 8 groups of 8. Grid = 1024 blocks x 128 threads:
//   bid = b*64 + tl;  tl<8: diagonal tile (gi=gj=tl);
//   tl>=8: t8=tl-8, H=t8&1 (half), pair=t8>>1 -> (gi<gj).
// Off-diag block (gi,gj,H) owns binary rows:
//   side0 (local 0..31) : (I0+oi -> J0+oj), oi in H-half of I, oj in J
//   side1 (local 32..63): (J0+oi -> I0+oj), oj in H-half of I
// and perms: dir0 {o0 in I_H, o1 in J} (p 0..31), dir1 {o0 in J, o1 in I_H}
// (p 32..63). Every binary row globally read EXACTLY once; its 48-ch
// projection lives in LDS and is consumed in-block -> no P round-trip.
// Phase A: waves 0/1 project rows (h = t>>6 picks P0/P1 channel half ->
// wave-uniform weight pointer -> s_load path). Then threads recompute unary
// projections for the block's 12 (8 diag) objects (redundant, tiny).
// Phase B: wave0 = 16 "max" channels (a=0 global max via wave-reduce +
// atomicMax; a=1 per-o0 max via sub-group shuffle + atomicMax into slots1);
// wave1 = 8 "direct" channels -> out2.
// ---------------------------------------------------------------------------
__global__ __launch_bounds__(128) void fused_kernel(
    const float* __restrict__ unary,     // [1024][128]
    const float* __restrict__ binary,    // [64512][128]
    const float* __restrict__ Wb,        // [128][48]
    const float* __restrict__ WuT,       // [48][128]
    const float* __restrict__ base,      // [16][24]
    const float* __restrict__ ork,       // [3][8]
    unsigned* __restrict__ max0,         // [128]
    unsigned* __restrict__ slots1,       // [1024][8]
    float* __restrict__ out)             // [16]+[1024]+[64512]
{
    __shared__ float proj2[48][65];      // [chan][local row]
    __shared__ float upro[48][13];       // [chan][local object]

    const int bid = blockIdx.x;
    const int b   = bid >> 6;
    const int tl  = bid & 63;
    const int t   = threadIdx.x;

    int gi, gj, H;
    bool diag;
    if (tl < 8) { diag = true; gi = gj = tl; H = 0; }
    else {
        diag = false;
        int t8 = tl - 8;
        H = t8 & 1;
        int pr = t8 >> 1;                 // 0..27 -> (gi<gj)
        int i = 0;
        while (pr >= 7 - i) { pr -= 7 - i; ++i; }
        gi = i; gj = i + 1 + pr;
    }
    const int I0 = gi * 8, J0 = gj * 8;

    // ---------------- phase A: binary row projections ----------------
    {
        const int r = t & 63;
        const int h = __builtin_amdgcn_readfirstlane(t >> 6);  // 0=P0ch, 1=P1ch
        int o, op, jv;
        if (diag) {
            const int oi = r >> 3, oj = r & 7;
            o = I0 + oi; op = I0 + oj;
            jv = op - ((oj > oi) ? 1 : 0);       // invalid oi==oj clamped below
        } else if (r < 32) {
            const int oi = H * 4 + (r >> 3), oj = r & 7;
            o = I0 + oi; op = J0 + oj;
            jv = op - 1;                          // op > o always (gi<gj)
        } else {
            const int rr = r - 32;
            const int oi = rr >> 2, oj = H * 4 + (rr & 3);
            o = J0 + oi; op = I0 + oj;
            jv = op;                              // op < o always
        }
        jv = min(jv, 62);
        const float* __restrict__ src = binary + ((size_t)(b * 64 + o) * 63 + jv) * 128;
        const float* __restrict__ W   = Wb + h * 24;

        float acc[24];
        #pragma unroll
        for (int n = 0; n < 24; ++n) acc[n] = 0.f;
        const float4* rp = (const float4*)src;
        #pragma unroll 4
        for (int k4 = 0; k4 < 32; ++k4) {
            float4 a = rp[k4];
            const float* wk = W + k4 * 4 * 48;
            #pragma unroll
            for (int q = 0; q < 4; ++q) {
                float av = (q == 0) ? a.x : (q == 1) ? a.y : (q == 2) ? a.z : a.w;
                const float* w = wk + q * 48;
                #pragma unroll
                for (int n = 0; n < 24; ++n) acc[n] = fmaf(av, w[n], acc[n]);
            }
        }
        #pragma unroll
        for (int n = 0; n < 24; ++n) proj2[h * 24 + n][r] = acc[n];
    }

    // ---------------- phase A2: unary projections (redundant per block) ----
    {
        const int nObj = diag ? 8 : 12;
        if (t < nObj * 8) {
            const int u = t >> 3, nb = t & 7, n0 = nb * 6;
            const int obj = diag ? (I0 + u)
                                 : (u < 4 ? (I0 + H * 4 + u) : (J0 + u - 4));
            const float4* su = (const float4*)(unary + (size_t)(b * 64 + obj) * 128);
            float a6[6];
            #pragma unroll
            for (int j = 0; j < 6; ++j) a6[j] = 0.f;
            #pragma unroll 4
            for (int k4 = 0; k4 < 32; ++k4) {
                float4 a = su[k4];
                #pragma unroll
                for (int j = 0; j < 6; ++j) {
                    float4 w = ((const float4*)(WuT + (n0 + j) * 128))[k4];
                    a6[j] = fmaf(a.x, w.x, fmaf(a.y, w.y, fmaf(a.z, w.z, fmaf(a.w, w.w, a6[j]))));
                }
            }
            #pragma unroll
            for (int j = 0; j < 6; ++j) upro[n0 + j][u] = a6[j];
        }
    }
    __syncthreads();

    // ---------------- phase B: combine ----------------
    const int p = t & 63;
    int o0, o1, r0, r1, u0, u1, j01;
    bool valid;
    if (diag) {
        const int qi = p >> 3, qj = p & 7;
        valid = (qi != qj);
        o0 = I0 + qi; o1 = I0 + qj;
        r0 = p; r1 = qj * 8 + qi;
        u0 = qi; u1 = qj;
        j01 = o1 - ((qj > qi) ? 1 : 0);
    } else if (p < 32) {                  // dir0: o0 in I_H, o1 in J
        const int qi = p >> 3, qj = p & 7;
        valid = true;
        o0 = I0 + H * 4 + qi; o1 = J0 + qj;
        r0 = p; r1 = 32 + qj * 4 + qi;
        u0 = qi; u1 = 4 + qj;
        j01 = o1 - 1;
    } else {                              // dir1: o0 in J, o1 in I_H
        const int pp = p - 32;
        const int qi = pp >> 2, qj = pp & 3;
        valid = true;
        o0 = J0 + qi; o1 = I0 + H * 4 + qj;
        r0 = 32 + qi * 4 + qj; r1 = qj * 8 + qi;
        u0 = 4 + qi; u1 = qj;
        j01 = o1;
    }
    const float* pb = base + b * 24;      // uniform -> s_load

    if (t >= 64) {
        // wave1: channels 16..23 -> out2
        float v = 0.f, b2 = 0.f;
        #pragma unroll
        for (int c = 0; c < 8; ++c) {
            const int ch = 16 + c;
            float x = pb[ch] + upro[ch][u0] + upro[24 + ch][u1]
                    + proj2[ch][r0] + proj2[24 + ch][r1];
            x = fast_tanh(x);
            float k = ork[16 + c];
            v  = fmaf(x, k, v);
            b2 = fmaf(k, k, b2);
        }
        if (valid) out[16 + 1024 + (b * 64 + o0) * 63 + j01] = v + b2 * TANH_THR - THR_F;
        return;
    }

    // wave0: channels 0..15
    float th[16];
    #pragma unroll
    for (int c = 0; c < 16; ++c) {
        float x = pb[c] + upro[c][u0] + upro[24 + c][u1]
                + proj2[c][r0] + proj2[24 + c][r1];
        th[c] = fast_tanh(x);
    }
    if (!valid) {
        #pragma unroll
        for (int c = 0; c < 16; ++c) th[c] = -2.f;
    }

    // a=0: global max over all perms of this block (whole wave0)
    #pragma unroll
    for (int c = 0; c < 8; ++c) {
        float v = th[c];
        #pragma unroll
        for (int m = 32; m; m >>= 1) v = fmaxf(v, __shfl_xor(v, m, 64));
        th[c] = v;
    }
    if (p == 0) {
        #pragma unroll
        for (int c = 0; c < 8; ++c)
            atomicMax(&max0[b * 8 + c], fkey(th[c]));
    }

    // a=1: per-(b,o0) max over this block's o1 range
    float m4[8], m8[8];
    #pragma unroll
    for (int c = 0; c < 8; ++c) {
        float v = th[8 + c];
        v = fmaxf(v, __shfl_xor(v, 1, 64));
        v = fmaxf(v, __shfl_xor(v, 2, 64));
        m4[c] = v;
        m8[c] = fmaxf(v, __shfl_xor(v, 4, 64));
    }
    const bool emit8 = (diag || p < 32) && ((p & 7) == 0);  // groups of 8 (qj)
    const bool emit4 = (!diag && p >= 32) && ((p & 3) == 0);// groups of 4 (qj')
    if (emit8) {
        #pragma unroll
        for (int c = 0; c < 8; ++c)
            atomicMax(&slots1[(b * 64 + o0) * 8 + c], fkey(m8[c]));
    }
    if (emit4) {
        #pragma unroll
        for (int c = 0; c < 8; ++c)
            atomicMax(&slots1[(b * 64 + o0) * 8 + c], fkey(m4[c]));
    }
}

// ---------------------------------------------------------------------------
// Kernel 2: finalize out0 (from max0) and out1 (from slots1)
// Grid = 5 blocks x 256.
// ---------------------------------------------------------------------------
__global__ __launch_bounds__(256) void finalize_kernel(
    const unsigned* __restrict__ max0,    // [128]
    const unsigned* __restrict__ slots1,  // [1024][8]
    const float* __restrict__ ork,
    float* __restrict__ out)
{
    const int bid = blockIdx.x, t = threadIdx.x;
    if (bid < 4) {
        const int i = bid * 256 + t;      // (b,o0) 0..1023
        float v = 0.f, bb = 0.f;
        #pragma unroll
        for (int c = 0; c < 8; ++c) {
            float m = fdecode(slots1[i * 8 + c]);
            float k = ork[8 + c];
            v  = fmaf(m, k, v);
            bb = fmaf(k, k, bb);
        }
        out[16 + i] = v + bb * TANH_THR - THR_F;
    } else if (t < 16) {
        float v = 0.f, bb = 0.f;
        #pragma unroll
        for (int c = 0; c < 8; ++c) {
            float m = fdecode(max0[t * 8 + c]);
            float k = ork[c];
            v  = fmaf(m, k, v);
            bb = fmaf(k, k, bb);
        }
        out[t] = v + bb * TANH_THR - THR_F;
    }
}

// ---------------------------------------------------------------------------
// launcher
// ---------------------------------------------------------------------------
extern "C" void kernel_launch(void* const* d_in, const int* in_sizes, int n_in,
                              void* d_out, int out_size, void* d_ws, size_t ws_size,
                              hipStream_t stream)
{
    const float* nullary = (const float*)d_in[0];   // (16,128)
    const float* unary   = (const float*)d_in[1];   // (16,64,128)
    const float* binary  = (const float*)d_in[2];   // (16,64,63,128)
    const float* andk    = (const float*)d_in[3];   // (3,8,640)
    const float* ork     = (const float*)d_in[4];   // (3,8)
    float* out = (float*)d_out;

    float* ws = (float*)d_ws;
    float*    Wb     = ws;                          // 6144
    float*    WuT    = ws + 6144;                   // 6144
    float*    base   = ws + 12288;                  // 384
    unsigned* max0   = (unsigned*)(ws + 12672);     // 128
    unsigned* slots1 = max0 + 128;                  // 8192

    prep_kernel<<<610, 64, 0, stream>>>(nullary, andk, Wb, WuT, base, max0);
    fused_kernel<<<1024, 128, 0, stream>>>(unary, binary, Wb, WuT, base, ork,
                                           max0, slots1, out);
    finalize_kernel<<<5, 256, 0, stream>>>(max0, slots1, ork, out);
}

// Round 7
// 135.054 us; speedup vs baseline: 1.1357x; 1.1357x over previous
//
#include <hip/hip_runtime.h>

#define THR_F     0.2f
#define TANH_THR  0.19737532f   // tanh(0.2), fp32-rounded

// ---------------------------------------------------------------------------
// helpers
// ---------------------------------------------------------------------------
__device__ __forceinline__ float fast_tanh(float x) {
    x = fminf(10.f, fmaxf(-10.f, x));
    float e = __expf(2.f * x);
    return (e - 1.f) * __builtin_amdgcn_rcpf(e + 1.f);
}

// monotone float <-> uint key for atomicMax on floats (all our values > -2)
__device__ __forceinline__ unsigned fkey(float f) {
    unsigned u = __float_as_uint(f);
    return (u & 0x80000000u) ? ~u : (u | 0x80000000u);
}
__device__ __forceinline__ float fdecode(unsigned u) {
    return __uint_as_float((u & 0x80000000u) ? (u & 0x7FFFFFFFu) : ~u);
}

// ---------------------------------------------------------------------------
// Kernel 0: prep. Grid = 610 blocks x 64 threads.
//  blocks 0..383   : (b,n) -> base[b*24+n] = dot(nullary[b],K[n,0:128])
//                    + THR - ssq[n]*tanh(THR)
//  blocks 384..479 : pack Wb[k][48] (binary cols 384:512|512:640) and
//                    Wu[k][48] (unary cols 128:256|256:384), both k-major
//  blocks 480..609 : zero max0[128] + slots1[8192]
// and_kernel layout: (3,8,640), ac = a*8+c rows of 640:
//   cols 0:128 null | 128:256 u(o0) | 256:384 u(o1) | 384:512 b(o0,j01) | 512:640 b(o1,j10)
// ---------------------------------------------------------------------------
__global__ __launch_bounds__(64) void prep_kernel(
    const float* __restrict__ nullary,   // [16][128]
    const float* __restrict__ andk,      // [24][640]
    float* __restrict__ Wb,              // [128][48]
    float* __restrict__ Wu,              // [128][48]
    float* __restrict__ base,            // [16][24]
    unsigned* __restrict__ zzero)        // max0[128] ++ slots1[8192]
{
    const int bid = blockIdx.x;
    const int t   = threadIdx.x;
    if (bid < 384) {
        const int b = bid / 24, n = bid % 24;
        const float* w  = andk + n * 640;
        const float* nu = nullary + b * 128;
        float s = 0.f;
        #pragma unroll
        for (int i = 0; i < 10; ++i) { float v = w[t + i * 64]; s = fmaf(v, v, s); }
        float d = fmaf(nu[t], w[t], 0.f);
        d = fmaf(nu[t + 64], w[t + 64], d);
        #pragma unroll
        for (int m = 32; m; m >>= 1) {
            s += __shfl_xor(s, m, 64);
            d += __shfl_xor(d, m, 64);
        }
        if (t == 0) base[bid] = d + THR_F - s * TANH_THR;
    } else if (bid < 480) {
        const int i = (bid - 384) * 64 + t;   // 0..6143
        const int k = i / 48, n = i % 48;
        const int ac   = (n < 24) ? n : n - 24;
        const int colb = (n < 24) ? 384 : 512;
        const int colu = (n < 24) ? 128 : 256;
        Wb[i] = andk[ac * 640 + colb + k];
        Wu[i] = andk[ac * 640 + colu + k];
    } else {
        const int idx = (bid - 480) * 64 + t;
        if (idx < 8320) zzero[idx] = 0u;
    }
}

// ---------------------------------------------------------------------------
// Kernel 0b: unary projections, computed ONCE (R6's per-block recompute was
// the 76us regression: 18K scattered loads/block). Structure proven in R5.
// Grid = 16 blocks x 256 (4 waves). Wave w: channel slice w*12; lane = row.
// Weight pointer wave-uniform -> s_load path. Writes U[1024][48].
// ---------------------------------------------------------------------------
__global__ __launch_bounds__(256) void uproj_kernel(
    const float* __restrict__ unary,     // [1024][128]
    const float* __restrict__ Wu,        // [128][48]
    float* __restrict__ U)               // [1024][48]
{
    const int wave = __builtin_amdgcn_readfirstlane((int)(threadIdx.x >> 6)); // 0..3
    const int lane = threadIdx.x & 63;
    const int row  = blockIdx.x * 64 + lane;
    const float* __restrict__ W   = Wu + wave * 12;
    const float* __restrict__ src = unary + (size_t)row * 128;

    float acc[12];
    #pragma unroll
    for (int n = 0; n < 12; ++n) acc[n] = 0.f;

    const float4* rp = (const float4*)src;
    #pragma unroll 8
    for (int k4 = 0; k4 < 32; ++k4) {
        float4 a = rp[k4];
        const float* wk = W + k4 * 4 * 48;
        #pragma unroll
        for (int q = 0; q < 4; ++q) {
            float av = (q == 0) ? a.x : (q == 1) ? a.y : (q == 2) ? a.z : a.w;
            const float* w = wk + q * 48;
            #pragma unroll
            for (int n = 0; n < 12; ++n) acc[n] = fmaf(av, w[n], acc[n]);
        }
    }

    float4* d4 = (float4*)(U + (size_t)row * 48 + wave * 12);
    #pragma unroll
    for (int i = 0; i < 3; ++i)
        d4[i] = make_float4(acc[i*4+0], acc[i*4+1], acc[i*4+2], acc[i*4+3]);
}

// ---------------------------------------------------------------------------
// Kernel 1: FUSED binary projection + tanh + reductions + OR stage.
// Objects tiled into 8 groups of 8. Grid = 1024 blocks x 128 threads:
//   bid = b*64 + tl;  tl<8: diagonal tile (gi=gj=tl);
//   tl>=8: t8=tl-8, H=t8&1 (half), pair=t8>>1 -> (gi<gj).
// Every binary row globally read EXACTLY once (per half-wave pair); its 48-ch
// projection lives in LDS and is consumed in-block -> no P round-trip.
// Phase A: both waves project the 64 rows (h = t>>6 picks channel half ->
// wave-uniform weight pointer -> s_load). Phase A2: tiny LDS fill of the
// precomputed U rows (144 float4 loads/block). Phase B as R6 (verified).
// ---------------------------------------------------------------------------
__global__ __launch_bounds__(128) void fused_kernel(
    const float* __restrict__ U,         // [1024][48]
    const float* __restrict__ binary,    // [64512][128]
    const float* __restrict__ Wb,        // [128][48]
    const float* __restrict__ base,      // [16][24]
    const float* __restrict__ ork,       // [3][8]
    unsigned* __restrict__ max0,         // [128]
    unsigned* __restrict__ slots1,       // [1024][8]
    float* __restrict__ out)             // [16]+[1024]+[64512]
{
    __shared__ float proj2[48][65];      // [chan][local row]
    __shared__ float upro[12][52];       // [local object][chan] (52: pad, 16B-mult)

    const int bid = blockIdx.x;
    const int b   = bid >> 6;
    const int tl  = bid & 63;
    const int t   = threadIdx.x;

    int gi, gj, H;
    bool diag;
    if (tl < 8) { diag = true; gi = gj = tl; H = 0; }
    else {
        diag = false;
        int t8 = tl - 8;
        H = t8 & 1;
        int pr = t8 >> 1;                 // 0..27 -> (gi<gj)
        int i = 0;
        while (pr >= 7 - i) { pr -= 7 - i; ++i; }
        gi = i; gj = i + 1 + pr;
    }
    const int I0 = gi * 8, J0 = gj * 8;
    const int nObj = diag ? 8 : 12;

    // ---------------- phase A2: load precomputed unary projections ---------
    for (int i = t; i < nObj * 12; i += 128) {
        const int u = i / 12, q = i % 12;
        const int obj = diag ? (I0 + u)
                             : (u < 4 ? (I0 + H * 4 + u) : (J0 + u - 4));
        float4 v = ((const float4*)(U + (size_t)(b * 64 + obj) * 48))[q];
        *((float4*)&upro[u][q * 4]) = v;
    }

    // ---------------- phase A: binary row projections ----------------
    {
        const int r = t & 63;
        const int h = __builtin_amdgcn_readfirstlane(t >> 6);  // 0=ch0..23, 1=ch24..47
        int o, op, jv;
        if (diag) {
            const int oi = r >> 3, oj = r & 7;
            o = I0 + oi; op = I0 + oj;
            jv = op - ((oj > oi) ? 1 : 0);       // invalid oi==oj clamped below
        } else if (r < 32) {
            const int oi = H * 4 + (r >> 3), oj = r & 7;
            o = I0 + oi; op = J0 + oj;
            jv = op - 1;                          // op > o always (gi<gj)
        } else {
            const int rr = r - 32;
            const int oi = rr >> 2, oj = H * 4 + (rr & 3);
            o = J0 + oi; op = I0 + oj;
            jv = op;                              // op < o always
        }
        jv = min(jv, 62);
        const float* __restrict__ src = binary + ((size_t)(b * 64 + o) * 63 + jv) * 128;
        const float* __restrict__ W   = Wb + h * 24;

        float acc[24];
        #pragma unroll
        for (int n = 0; n < 24; ++n) acc[n] = 0.f;
        const float4* rp = (const float4*)src;
        #pragma unroll 4
        for (int k4 = 0; k4 < 32; ++k4) {
            float4 a = rp[k4];
            const float* wk = W + k4 * 4 * 48;
            #pragma unroll
            for (int q = 0; q < 4; ++q) {
                float av = (q == 0) ? a.x : (q == 1) ? a.y : (q == 2) ? a.z : a.w;
                const float* w = wk + q * 48;
                #pragma unroll
                for (int n = 0; n < 24; ++n) acc[n] = fmaf(av, w[n], acc[n]);
            }
        }
        #pragma unroll
        for (int n = 0; n < 24; ++n) proj2[h * 24 + n][r] = acc[n];
    }
    __syncthreads();

    // ---------------- phase B: combine ----------------
    const int p = t & 63;
    int o0, o1, r0, r1, u0, u1, j01;
    bool valid;
    if (diag) {
        const int qi = p >> 3, qj = p & 7;
        valid = (qi != qj);
        o0 = I0 + qi; o1 = I0 + qj;
        r0 = p; r1 = qj * 8 + qi;
        u0 = qi; u1 = qj;
        j01 = o1 - ((qj > qi) ? 1 : 0);
    } else if (p < 32) {                  // dir0: o0 in I_H, o1 in J
        const int qi = p >> 3, qj = p & 7;
        valid = true;
        o0 = I0 + H * 4 + qi; o1 = J0 + qj;
        r0 = p; r1 = 32 + qj * 4 + qi;
        u0 = qi; u1 = 4 + qj;
        j01 = o1 - 1;
    } else {                              // dir1: o0 in J, o1 in I_H
        const int pp = p - 32;
        const int qi = pp >> 2, qj = pp & 3;
        valid = true;
        o0 = J0 + qi; o1 = I0 + H * 4 + qj;
        r0 = 32 + qi * 4 + qj; r1 = qj * 8 + qi;
        u0 = 4 + qi; u1 = qj;
        j01 = o1;
    }
    const float* pb = base + b * 24;      // uniform -> s_load

    if (t >= 64) {
        // wave1: channels 16..23 -> out2
        float v = 0.f, b2 = 0.f;
        #pragma unroll
        for (int c = 0; c < 8; ++c) {
            const int ch = 16 + c;
            float x = pb[ch] + upro[u0][ch] + upro[u1][24 + ch]
                    + proj2[ch][r0] + proj2[24 + ch][r1];
            x = fast_tanh(x);
            float k = ork[16 + c];
            v  = fmaf(x, k, v);
            b2 = fmaf(k, k, b2);
        }
        if (valid) out[16 + 1024 + (b * 64 + o0) * 63 + j01] = v + b2 * TANH_THR - THR_F;
        return;
    }

    // wave0: channels 0..15
    float th[16];
    #pragma unroll
    for (int c = 0; c < 16; ++c) {
        float x = pb[c] + upro[u0][c] + upro[u1][24 + c]
                + proj2[c][r0] + proj2[24 + c][r1];
        th[c] = fast_tanh(x);
    }
    if (!valid) {
        #pragma unroll
        for (int c = 0; c < 16; ++c) th[c] = -2.f;
    }

    // a=0: global max over all perms of this block (whole wave0)
    #pragma unroll
    for (int c = 0; c < 8; ++c) {
        float v = th[c];
        #pragma unroll
        for (int m = 32; m; m >>= 1) v = fmaxf(v, __shfl_xor(v, m, 64));
        th[c] = v;
    }
    if (p == 0) {
        #pragma unroll
        for (int c = 0; c < 8; ++c)
            atomicMax(&max0[b * 8 + c], fkey(th[c]));
    }

    // a=1: per-(b,o0) max over this block's o1 range
    float m4[8], m8[8];
    #pragma unroll
    for (int c = 0; c < 8; ++c) {
        float v = th[8 + c];
        v = fmaxf(v, __shfl_xor(v, 1, 64));
        v = fmaxf(v, __shfl_xor(v, 2, 64));
        m4[c] = v;
        m8[c] = fmaxf(v, __shfl_xor(v, 4, 64));
    }
    const bool emit8 = (diag || p < 32) && ((p & 7) == 0);  // groups of 8 (qj)
    const bool emit4 = (!diag && p >= 32) && ((p & 3) == 0);// groups of 4 (qj')
    if (emit8) {
        #pragma unroll
        for (int c = 0; c < 8; ++c)
            atomicMax(&slots1[(b * 64 + o0) * 8 + c], fkey(m8[c]));
    }
    if (emit4) {
        #pragma unroll
        for (int c = 0; c < 8; ++c)
            atomicMax(&slots1[(b * 64 + o0) * 8 + c], fkey(m4[c]));
    }
}

// ---------------------------------------------------------------------------
// Kernel 2: finalize out0 (from max0) and out1 (from slots1)
// Grid = 5 blocks x 256.
// ---------------------------------------------------------------------------
__global__ __launch_bounds__(256) void finalize_kernel(
    const unsigned* __restrict__ max0,    // [128]
    const unsigned* __restrict__ slots1,  // [1024][8]
    const float* __restrict__ ork,
    float* __restrict__ out)
{
    const int bid = blockIdx.x, t = threadIdx.x;
    if (bid < 4) {
        const int i = bid * 256 + t;      // (b,o0) 0..1023
        float v = 0.f, bb = 0.f;
        #pragma unroll
        for (int c = 0; c < 8; ++c) {
            float m = fdecode(slots1[i * 8 + c]);
            float k = ork[8 + c];
            v  = fmaf(m, k, v);
            bb = fmaf(k, k, bb);
        }
        out[16 + i] = v + bb * TANH_THR - THR_F;
    } else if (t < 16) {
        float v = 0.f, bb = 0.f;
        #pragma unroll
        for (int c = 0; c < 8; ++c) {
            float m = fdecode(max0[t * 8 + c]);
            float k = ork[c];
            v  = fmaf(m, k, v);
            bb = fmaf(k, k, bb);
        }
        out[t] = v + bb * TANH_THR - THR_F;
    }
}

// ---------------------------------------------------------------------------
// launcher
// ---------------------------------------------------------------------------
extern "C" void kernel_launch(void* const* d_in, const int* in_sizes, int n_in,
                              void* d_out, int out_size, void* d_ws, size_t ws_size,
                              hipStream_t stream)
{
    const float* nullary = (const float*)d_in[0];   // (16,128)
    const float* unary   = (const float*)d_in[1];   // (16,64,128)
    const float* binary  = (const float*)d_in[2];   // (16,64,63,128)
    const float* andk    = (const float*)d_in[3];   // (3,8,640)
    const float* ork     = (const float*)d_in[4];   // (3,8)
    float* out = (float*)d_out;

    float* ws = (float*)d_ws;
    float*    Wb     = ws;                          // 6144
    float*    Wu     = ws + 6144;                   // 6144
    float*    base   = ws + 12288;                  // 384
    float*    U      = ws + 12672;                  // 49152
    unsigned* max0   = (unsigned*)(ws + 61824);     // 128
    unsigned* slots1 = max0 + 128;                  // 8192

    prep_kernel<<<610, 64, 0, stream>>>(nullary, andk, Wb, Wu, base, max0);
    uproj_kernel<<<16, 256, 0, stream>>>(unary, Wu, U);
    fused_kernel<<<1024, 128, 0, stream>>>(U, binary, Wb, base, ork,
                                           max0, slots1, out);
    finalize_kernel<<<5, 256, 0, stream>>>(max0, slots1, ork, out);
}

// Round 8
// 133.937 us; speedup vs baseline: 1.1452x; 1.0083x over previous
//
#include <hip/hip_runtime.h>

#define THR_F     0.2f
#define TANH_THR  0.19737532f   // tanh(0.2), fp32-rounded

// ---------------------------------------------------------------------------
// helpers
// ---------------------------------------------------------------------------
__device__ __forceinline__ float fast_tanh(float x) {
    x = fminf(10.f, fmaxf(-10.f, x));
    float e = __expf(2.f * x);
    return (e - 1.f) * __builtin_amdgcn_rcpf(e + 1.f);
}

// monotone float <-> uint key for atomicMax on floats (all our values > -2)
__device__ __forceinline__ unsigned fkey(float f) {
    unsigned u = __float_as_uint(f);
    return (u & 0x80000000u) ? ~u : (u | 0x80000000u);
}
__device__ __forceinline__ float fdecode(unsigned u) {
    return __uint_as_float((u & 0x80000000u) ? (u & 0x7FFFFFFFu) : ~u);
}

// ---------------------------------------------------------------------------
// Kernel 0: prep. Grid = 610 blocks x 64 threads.
//  blocks 0..383   : (b,n) -> base[b*24+n] = dot(nullary[b],K[n,0:128])
//                    + THR - ssq[n]*tanh(THR)
//  blocks 384..479 : pack Wb[k][48] (binary cols 384:512|512:640) and
//                    Wu[k][48] (unary cols 128:256|256:384), both k-major
//  blocks 480..609 : zero max0[128] + slots1[8192]
// and_kernel layout: (3,8,640), ac = a*8+c rows of 640:
//   cols 0:128 null | 128:256 u(o0) | 256:384 u(o1) | 384:512 b(o0,j01) | 512:640 b(o1,j10)
// ---------------------------------------------------------------------------
__global__ __launch_bounds__(64) void prep_kernel(
    const float* __restrict__ nullary,   // [16][128]
    const float* __restrict__ andk,      // [24][640]
    float* __restrict__ Wb,              // [128][48]
    float* __restrict__ Wu,              // [128][48]
    float* __restrict__ base,            // [16][24]
    unsigned* __restrict__ zzero)        // max0[128] ++ slots1[8192]
{
    const int bid = blockIdx.x;
    const int t   = threadIdx.x;
    if (bid < 384) {
        const int b = bid / 24, n = bid % 24;
        const float* w  = andk + n * 640;
        const float* nu = nullary + b * 128;
        float s = 0.f;
        #pragma unroll
        for (int i = 0; i < 10; ++i) { float v = w[t + i * 64]; s = fmaf(v, v, s); }
        float d = fmaf(nu[t], w[t], 0.f);
        d = fmaf(nu[t + 64], w[t + 64], d);
        #pragma unroll
        for (int m = 32; m; m >>= 1) {
            s += __shfl_xor(s, m, 64);
            d += __shfl_xor(d, m, 64);
        }
        if (t == 0) base[bid] = d + THR_F - s * TANH_THR;
    } else if (bid < 480) {
        const int i = (bid - 384) * 64 + t;   // 0..6143
        const int k = i / 48, n = i % 48;
        const int ac   = (n < 24) ? n : n - 24;
        const int colb = (n < 24) ? 384 : 512;
        const int colu = (n < 24) ? 128 : 256;
        Wb[i] = andk[ac * 640 + colb + k];
        Wu[i] = andk[ac * 640 + colu + k];
    } else {
        const int idx = (bid - 480) * 64 + t;
        if (idx < 8320) zzero[idx] = 0u;
    }
}

// ---------------------------------------------------------------------------
// Kernel 0b: unary projections, once. Grid = 16 x 256 (R5-proven structure).
// ---------------------------------------------------------------------------
__global__ __launch_bounds__(256) void uproj_kernel(
    const float* __restrict__ unary,     // [1024][128]
    const float* __restrict__ Wu,        // [128][48]
    float* __restrict__ U)               // [1024][48]
{
    const int wave = __builtin_amdgcn_readfirstlane((int)(threadIdx.x >> 6)); // 0..3
    const int lane = threadIdx.x & 63;
    const int row  = blockIdx.x * 64 + lane;
    const float* __restrict__ W   = Wu + wave * 12;
    const float* __restrict__ src = unary + (size_t)row * 128;

    float acc[12];
    #pragma unroll
    for (int n = 0; n < 12; ++n) acc[n] = 0.f;

    const float4* rp = (const float4*)src;
    #pragma unroll 8
    for (int k4 = 0; k4 < 32; ++k4) {
        float4 a = rp[k4];
        const float* wk = W + k4 * 4 * 48;
        #pragma unroll
        for (int q = 0; q < 4; ++q) {
            float av = (q == 0) ? a.x : (q == 1) ? a.y : (q == 2) ? a.z : a.w;
            const float* w = wk + q * 48;
            #pragma unroll
            for (int n = 0; n < 12; ++n) acc[n] = fmaf(av, w[n], acc[n]);
        }
    }

    float4* d4 = (float4*)(U + (size_t)row * 48 + wave * 12);
    #pragma unroll
    for (int i = 0; i < 3; ++i)
        d4[i] = make_float4(acc[i*4+0], acc[i*4+1], acc[i*4+2], acc[i*4+3]);
}

// ---------------------------------------------------------------------------
// Kernel 1: FUSED binary projection + tanh + reductions + OR stage.
// Objects tiled into 8 groups of 8. Grid = 1024 blocks x 256 THREADS (4 waves
// -> 16 waves/CU, matching R5-proj's proven latency-hiding; R7's 128-thread
// version sat at 8 waves/CU and was 5x slower on the same divergent loads).
//   bid = b*64 + tl;  tl<8: diagonal tile; tl>=8: t8=tl-8, H=t8&1, pair=t8>>1.
// Phase A: thread (r = t&63, h = t>>6) computes the 12-channel slice h of
// binary row r (row read by 4 threads in 4 waves -> L1/L2 re-read, HBM once).
// Phase B: wave0 = a0 global max, wave2 = a1 per-o0 max, wave1 = a2/out2,
// wave3 idle. Index math identical to the absmax-0.0 R7 version.
// ---------------------------------------------------------------------------
__global__ __launch_bounds__(256) void fused_kernel(
    const float* __restrict__ U,         // [1024][48]
    const float* __restrict__ binary,    // [64512][128]
    const float* __restrict__ Wb,        // [128][48]
    const float* __restrict__ base,      // [16][24]
    const float* __restrict__ ork,       // [3][8]
    unsigned* __restrict__ max0,         // [128]
    unsigned* __restrict__ slots1,       // [1024][8]
    float* __restrict__ out)             // [16]+[1024]+[64512]
{
    __shared__ float proj2[48][65];      // [chan][local row]
    __shared__ float upro[12][52];       // [local object][chan]

    const int bid = blockIdx.x;
    const int b   = bid >> 6;
    const int tl  = bid & 63;
    const int t   = threadIdx.x;

    int gi, gj, H;
    bool diag;
    if (tl < 8) { diag = true; gi = gj = tl; H = 0; }
    else {
        diag = false;
        int t8 = tl - 8;
        H = t8 & 1;
        int pr = t8 >> 1;                 // 0..27 -> (gi<gj)
        int i = 0;
        while (pr >= 7 - i) { pr -= 7 - i; ++i; }
        gi = i; gj = i + 1 + pr;
    }
    const int I0 = gi * 8, J0 = gj * 8;
    const int nObj = diag ? 8 : 12;

    // ---------------- phase A2: load precomputed unary projections ---------
    if (t < nObj * 12) {
        const int u = t / 12, q = t % 12;
        const int obj = diag ? (I0 + u)
                             : (u < 4 ? (I0 + H * 4 + u) : (J0 + u - 4));
        float4 v = ((const float4*)(U + (size_t)(b * 64 + obj) * 48))[q];
        *((float4*)&upro[u][q * 4]) = v;
    }

    // ---------------- phase A: binary row projections (12 ch/thread) -------
    {
        const int r = t & 63;
        const int h = __builtin_amdgcn_readfirstlane(t >> 6);  // 0..3 channel slice
        int o, op, jv;
        if (diag) {
            const int oi = r >> 3, oj = r & 7;
            o = I0 + oi; op = I0 + oj;
            jv = op - ((oj > oi) ? 1 : 0);       // invalid oi==oj clamped below
        } else if (r < 32) {
            const int oi = H * 4 + (r >> 3), oj = r & 7;
            o = I0 + oi; op = J0 + oj;
            jv = op - 1;                          // op > o always (gi<gj)
        } else {
            const int rr = r - 32;
            const int oi = rr >> 2, oj = H * 4 + (rr & 3);
            o = J0 + oi; op = I0 + oj;
            jv = op;                              // op < o always
        }
        jv = min(jv, 62);
        const float* __restrict__ src = binary + ((size_t)(b * 64 + o) * 63 + jv) * 128;
        const float* __restrict__ W   = Wb + h * 12;

        float acc[12];
        #pragma unroll
        for (int n = 0; n < 12; ++n) acc[n] = 0.f;
        const float4* rp = (const float4*)src;
        #pragma unroll 8
        for (int k4 = 0; k4 < 32; ++k4) {
            float4 a = rp[k4];
            const float* wk = W + k4 * 4 * 48;
            #pragma unroll
            for (int q = 0; q < 4; ++q) {
                float av = (q == 0) ? a.x : (q == 1) ? a.y : (q == 2) ? a.z : a.w;
                const float* w = wk + q * 48;
                #pragma unroll
                for (int n = 0; n < 12; ++n) acc[n] = fmaf(av, w[n], acc[n]);
            }
        }
        #pragma unroll
        for (int n = 0; n < 12; ++n) proj2[h * 12 + n][r] = acc[n];
    }
    __syncthreads();

    // ---------------- phase B: combine ----------------
    const int w = __builtin_amdgcn_readfirstlane(t >> 6);  // 0..3
    if (w == 3) return;                                    // barrier already passed

    const int p = t & 63;
    int o0, o1, r0, r1, u0, u1, j01;
    bool valid;
    if (diag) {
        const int qi = p >> 3, qj = p & 7;
        valid = (qi != qj);
        o0 = I0 + qi; o1 = I0 + qj;
        r0 = p; r1 = qj * 8 + qi;
        u0 = qi; u1 = qj;
        j01 = o1 - ((qj > qi) ? 1 : 0);
    } else if (p < 32) {                  // dir0: o0 in I_H, o1 in J
        const int qi = p >> 3, qj = p & 7;
        valid = true;
        o0 = I0 + H * 4 + qi; o1 = J0 + qj;
        r0 = p; r1 = 32 + qj * 4 + qi;
        u0 = qi; u1 = 4 + qj;
        j01 = o1 - 1;
    } else {                              // dir1: o0 in J, o1 in I_H
        const int pp = p - 32;
        const int qi = pp >> 2, qj = pp & 3;
        valid = true;
        o0 = J0 + qi; o1 = I0 + H * 4 + qj;
        r0 = 32 + qi * 4 + qj; r1 = qj * 8 + qi;
        u0 = 4 + qi; u1 = qj;
        j01 = o1;
    }
    const float* pb = base + b * 24;      // uniform -> s_load

    if (w == 1) {
        // a=2: channels 16..23 -> out2
        float v = 0.f, b2 = 0.f;
        #pragma unroll
        for (int c = 0; c < 8; ++c) {
            const int ch = 16 + c;
            float x = pb[ch] + upro[u0][ch] + upro[u1][24 + ch]
                    + proj2[ch][r0] + proj2[24 + ch][r1];
            x = fast_tanh(x);
            float k = ork[16 + c];
            v  = fmaf(x, k, v);
            b2 = fmaf(k, k, b2);
        }
        if (valid) out[16 + 1024 + (b * 64 + o0) * 63 + j01] = v + b2 * TANH_THR - THR_F;
        return;
    }

    const int cb = (w == 0) ? 0 : 8;      // wave0 -> a=0 (ch 0..7), wave2 -> a=1 (ch 8..15)
    float th[8];
    #pragma unroll
    for (int c = 0; c < 8; ++c) {
        const int ch = cb + c;
        float x = pb[ch] + upro[u0][ch] + upro[u1][24 + ch]
                + proj2[ch][r0] + proj2[24 + ch][r1];
        th[c] = fast_tanh(x);
    }
    if (!valid) {
        #pragma unroll
        for (int c = 0; c < 8; ++c) th[c] = -2.f;
    }

    if (w == 0) {
        // a=0: global max over this block's perms -> atomicMax
        #pragma unroll
        for (int c = 0; c < 8; ++c) {
            float v = th[c];
            #pragma unroll
            for (int m = 32; m; m >>= 1) v = fmaxf(v, __shfl_xor(v, m, 64));
            th[c] = v;
        }
        if (p == 0) {
            #pragma unroll
            for (int c = 0; c < 8; ++c)
                atomicMax(&max0[b * 8 + c], fkey(th[c]));
        }
        return;
    }

    // w == 2: a=1 per-(b,o0) max over this block's o1 range
    float m4[8], m8[8];
    #pragma unroll
    for (int c = 0; c < 8; ++c) {
        float v = th[c];
        v = fmaxf(v, __shfl_xor(v, 1, 64));
        v = fmaxf(v, __shfl_xor(v, 2, 64));
        m4[c] = v;
        m8[c] = fmaxf(v, __shfl_xor(v, 4, 64));
    }
    const bool emit8 = (diag || p < 32) && ((p & 7) == 0);  // groups of 8 (qj)
    const bool emit4 = (!diag && p >= 32) && ((p & 3) == 0);// groups of 4 (qj')
    if (emit8) {
        #pragma unroll
        for (int c = 0; c < 8; ++c)
            atomicMax(&slots1[(b * 64 + o0) * 8 + c], fkey(m8[c]));
    }
    if (emit4) {
        #pragma unroll
        for (int c = 0; c < 8; ++c)
            atomicMax(&slots1[(b * 64 + o0) * 8 + c], fkey(m4[c]));
    }
}

// ---------------------------------------------------------------------------
// Kernel 2: finalize out0 (from max0) and out1 (from slots1)
// Grid = 5 blocks x 256.
// ---------------------------------------------------------------------------
__global__ __launch_bounds__(256) void finalize_kernel(
    const unsigned* __restrict__ max0,    // [128]
    const unsigned* __restrict__ slots1,  // [1024][8]
    const float* __restrict__ ork,
    float* __restrict__ out)
{
    const int bid = blockIdx.x, t = threadIdx.x;
    if (bid < 4) {
        const int i = bid * 256 + t;      // (b,o0) 0..1023
        float v = 0.f, bb = 0.f;
        #pragma unroll
        for (int c = 0; c < 8; ++c) {
            float m = fdecode(slots1[i * 8 + c]);
            float k = ork[8 + c];
            v  = fmaf(m, k, v);
            bb = fmaf(k, k, bb);
        }
        out[16 + i] = v + bb * TANH_THR - THR_F;
    } else if (t < 16) {
        float v = 0.f, bb = 0.f;
        #pragma unroll
        for (int c = 0; c < 8; ++c) {
            float m = fdecode(max0[t * 8 + c]);
            float k = ork[c];
            v  = fmaf(m, k, v);
            bb = fmaf(k, k, bb);
        }
        out[t] = v + bb * TANH_THR - THR_F;
    }
}

// ---------------------------------------------------------------------------
// launcher
// ---------------------------------------------------------------------------
extern "C" void kernel_launch(void* const* d_in, const int* in_sizes, int n_in,
                              void* d_out, int out_size, void* d_ws, size_t ws_size,
                              hipStream_t stream)
{
    const float* nullary = (const float*)d_in[0];   // (16,128)
    const float* unary   = (const float*)d_in[1];   // (16,64,128)
    const float* binary  = (const float*)d_in[2];   // (16,64,63,128)
    const float* andk    = (const float*)d_in[3];   // (3,8,640)
    const float* ork     = (const float*)d_in[4];   // (3,8)
    float* out = (float*)d_out;

    float* ws = (float*)d_ws;
    float*    Wb     = ws;                          // 6144
    float*    Wu     = ws + 6144;                   // 6144
    float*    base   = ws + 12288;                  // 384
    float*    U      = ws + 12672;                  // 49152
    unsigned* max0   = (unsigned*)(ws + 61824);     // 128
    unsigned* slots1 = max0 + 128;                  // 8192

    prep_kernel<<<610, 64, 0, stream>>>(nullary, andk, Wb, Wu, base, max0);
    uproj_kernel<<<16, 256, 0, stream>>>(unary, Wu, U);
    fused_kernel<<<1024, 256, 0, stream>>>(U, binary, Wb, base, ork,
                                           max0, slots1, out);
    finalize_kernel<<<5, 256, 0, stream>>>(max0, slots1, ork, out);
}